// Round 5
// baseline (263.644 us; speedup 1.0000x reference)
//
#include <hip/hip_runtime.h>
#include <hip/hip_bf16.h>

#define D 128
#define NEG_SLOPE 0.1f
// bucket sort: 512 nodes per bucket; pack = (dstLocal<<17)|src  (valid: N < 2^17)
#define BSHIFT 9
#define BSIZE 512
#define SRCBITS 17
#define SRCMASK 0x1FFFF

typedef __attribute__((ext_vector_type(8))) short bf16x8;
typedef __attribute__((ext_vector_type(4))) float f32x4;
typedef __attribute__((ext_vector_type(2))) float f32x2;

__device__ inline unsigned short f2bf(float f) {
    unsigned u = __builtin_bit_cast(unsigned, f);
    u += 0x7fff + ((u >> 16) & 1);  // round-to-nearest-even
    return (unsigned short)(u >> 16);
}
__device__ inline float bflo2f(unsigned u) { return __builtin_bit_cast(float, u << 16); }
__device__ inline float bfhi2f(unsigned u) { return __builtin_bit_cast(float, u & 0xffff0000u); }

// ---------------- bucket histogram (LDS-aggregated) + fused W transpose ----------------
// blocks [0, nbE): edge counting; blocks [nbE, nbE+64): W transpose to bf16 Wt[n][k]
__global__ __launch_bounds__(256) void k_bucket_count(const int* __restrict__ dst,
                                                      int* __restrict__ bucketCnt, int E, int NB,
                                                      const float* __restrict__ W,
                                                      unsigned short* __restrict__ Wt) {
    int b = blockIdx.x;
    int nbE = gridDim.x - 64;
    if (b >= nbE) {
        int t = (b - nbE) * 256 + threadIdx.x;  // 0..16383
        int k = t >> 7, nn = t & 127;
        Wt[nn * D + k] = f2bf(W[k * D + nn]);
        return;
    }
    __shared__ int hist[256];
    int t = threadIdx.x;
    hist[t] = 0;
    __syncthreads();
    const int4* dst4 = (const int4*)dst;
#pragma unroll
    for (int j = 0; j < 4; j++) {
        int i4 = b * 1024 + j * 256 + t;
        int e = i4 * 4;
        if (e + 4 <= E) {
            int4 d = dst4[i4];
            atomicAdd(&hist[d.x >> BSHIFT], 1);
            atomicAdd(&hist[d.y >> BSHIFT], 1);
            atomicAdd(&hist[d.z >> BSHIFT], 1);
            atomicAdd(&hist[d.w >> BSHIFT], 1);
        } else {
            for (int k = e; k < E; k++) atomicAdd(&hist[dst[k] >> BSHIFT], 1);
        }
    }
    __syncthreads();
    if (t < NB && hist[t]) atomicAdd(&bucketCnt[t], hist[t]);
}

// ---------------- scan bucket counts (1 block); init cursor; sentinels ----------------
__global__ __launch_bounds__(256) void k_bucket_scan(const int* __restrict__ bucketCnt,
                                                     int* __restrict__ bucketBase, int* __restrict__ bucketCursor,
                                                     int* __restrict__ offs, int NB, int N, int E) {
    __shared__ int sh[256];
    int t = threadIdx.x;
    int v = (t < NB) ? bucketCnt[t] : 0;
    sh[t] = v;
    __syncthreads();
    for (int d = 1; d < 256; d <<= 1) {
        int y = 0;
        if (t >= d) y = sh[t - d];
        __syncthreads();
        sh[t] += y;
        __syncthreads();
    }
    if (t < NB) {
        int excl = sh[t] - v;
        bucketBase[t] = excl;
        bucketCursor[t] = excl;
    }
    if (t == 0) {
        bucketBase[NB] = E;
        offs[N] = E;  // CSR sentinel
    }
}

// ---------------- bucket scatter: packed edges into bucket regions ----------------
__global__ __launch_bounds__(256) void k_bucket_scatter(const int* __restrict__ src, const int* __restrict__ dst,
                                                        int* __restrict__ bucketCursor,
                                                        int* __restrict__ ebuf, int E, int NB) {
    __shared__ int cntL[256], baseL[256], curL[256];
    int t = threadIdx.x;
    cntL[t] = 0;
    curL[t] = 0;
    __syncthreads();

    const int4* src4 = (const int4*)src;
    const int4* dst4 = (const int4*)dst;
    int sv[16], dv[16];
    int nval[4];
#pragma unroll
    for (int j = 0; j < 4; j++) {
        int i4 = blockIdx.x * 1024 + j * 256 + t;
        int e = i4 * 4;
        if (e + 4 <= E) {
            int4 s = src4[i4];
            int4 d = dst4[i4];
            sv[j * 4] = s.x; sv[j * 4 + 1] = s.y; sv[j * 4 + 2] = s.z; sv[j * 4 + 3] = s.w;
            dv[j * 4] = d.x; dv[j * 4 + 1] = d.y; dv[j * 4 + 2] = d.z; dv[j * 4 + 3] = d.w;
            nval[j] = 4;
        } else {
            int c = 0;
            for (int k = e; k < E; k++, c++) { sv[j * 4 + c] = src[k]; dv[j * 4 + c] = dst[k]; }
            nval[j] = c;
        }
    }
    // phase 1: local histogram
#pragma unroll
    for (int j = 0; j < 4; j++)
        for (int k = 0; k < nval[j]; k++) atomicAdd(&cntL[dv[j * 4 + k] >> BSHIFT], 1);
    __syncthreads();
    // phase 2: one global reservation per touched bucket
    if (t < NB) {
        int c = cntL[t];
        if (c) baseL[t] = atomicAdd(&bucketCursor[t], c);
    }
    __syncthreads();
    // phase 3: write packed edges
#pragma unroll
    for (int j = 0; j < 4; j++)
        for (int k = 0; k < nval[j]; k++) {
            int d = dv[j * 4 + k];
            int b = d >> BSHIFT;
            int slot = atomicAdd(&curL[b], 1);
            ebuf[baseL[b] + slot] = ((d & (BSIZE - 1)) << SRCBITS) | sv[j * 4 + k];
        }
}

// ---------------- per-bucket CSR build: offs, dinv, sorted_src ----------------
__global__ __launch_bounds__(256) void k_bucket_csr(const int* __restrict__ ebuf, const int* __restrict__ bucketBase,
                                                    int* __restrict__ offs, float* __restrict__ dinv,
                                                    int* __restrict__ sorted_src, int N) {
    __shared__ int deg[BSIZE];
    __shared__ int wsum[4];
    int b = blockIdx.x, t = threadIdx.x, lane = t & 63, wave = t >> 6;
    int estart = bucketBase[b], eend = bucketBase[b + 1];
    int nstart = b << BSHIFT;

    deg[t] = 0;
    deg[t + 256] = 0;
    __syncthreads();
    for (int e = estart + t; e < eend; e += 256) atomicAdd(&deg[ebuf[e] >> SRCBITS], 1);
    __syncthreads();

    // exclusive scan of deg[512]; thread t owns elements 2t, 2t+1
    int d0 = deg[2 * t], d1 = deg[2 * t + 1];
    int sum = d0 + d1;
    int inc = sum;
    for (int d = 1; d < 64; d <<= 1) {
        int y = __shfl_up(inc, d, 64);
        if (lane >= d) inc += y;
    }
    int texcl = inc - sum;
    if (lane == 63) wsum[wave] = inc;
    __syncthreads();
    int woff = 0;
    for (int w = 0; w < wave; w++) woff += wsum[w];
    int e0 = woff + texcl;  // exclusive prefix before element 2t

    int i = nstart + 2 * t;
    if (i < N) { offs[i] = estart + e0; dinv[i] = rsqrtf((float)(d0 + 1)); }
    if (i + 1 < N) { offs[i + 1] = estart + e0 + d0; dinv[i + 1] = rsqrtf((float)(d1 + 1)); }
    __syncthreads();
    // reuse deg as cursor (init to exclusive offsets)
    deg[2 * t] = e0;
    deg[2 * t + 1] = e0 + d0;
    __syncthreads();
    for (int e = estart + t; e < eend; e += 256) {
        int v = ebuf[e];
        int pos = atomicAdd(&deg[v >> SRCBITS], 1);
        sorted_src[estart + pos] = v & SRCMASK;
    }
}

// ---------------- MFMA GEMM: h'(bf16) = (x @ W) * dinv[row] ----------------
__global__ __launch_bounds__(256) void k_gemm(const float* __restrict__ x,
                                              const unsigned short* __restrict__ Wt,
                                              const float* __restrict__ dinv,
                                              unsigned short* __restrict__ h, int n) {
    __shared__ unsigned short Wl[D * 136];
    int t = threadIdx.x;
    const uint4* Wg4 = (const uint4*)Wt;
#pragma unroll
    for (int j = 0; j < 8; j++) {
        int c = t + 256 * j;
        int row = c >> 4, kg = c & 15;
        *(uint4*)&Wl[row * 136 + kg * 8] = Wg4[row * 16 + kg];
    }
    __syncthreads();

    int lane = t & 63, wave = t >> 6;
    int quad = lane >> 4, mrow = lane & 15;
    int rbase = blockIdx.x * 128 + wave * 32;

    const float4* x4 = (const float4*)x;
    float4 a0[2][4], a1[2][4];
#pragma unroll
    for (int rt = 0; rt < 2; rt++) {
        int row = rbase + rt * 16 + mrow;
        long rowl = (row < n) ? row : (n - 1);
#pragma unroll
        for (int ks = 0; ks < 4; ks++) {
            long base = rowl * 32 + ks * 8 + quad * 2;
            a0[rt][ks] = x4[base];
            a1[rt][ks] = x4[base + 1];
        }
    }
    bf16x8 af[2][4];
#pragma unroll
    for (int rt = 0; rt < 2; rt++)
#pragma unroll
        for (int ks = 0; ks < 4; ks++) {
            bf16x8 f;
            f[0] = (short)f2bf(a0[rt][ks].x); f[1] = (short)f2bf(a0[rt][ks].y);
            f[2] = (short)f2bf(a0[rt][ks].z); f[3] = (short)f2bf(a0[rt][ks].w);
            f[4] = (short)f2bf(a1[rt][ks].x); f[5] = (short)f2bf(a1[rt][ks].y);
            f[6] = (short)f2bf(a1[rt][ks].z); f[7] = (short)f2bf(a1[rt][ks].w);
            af[rt][ks] = f;
        }

    f32x4 acc[2][8];
#pragma unroll
    for (int rt = 0; rt < 2; rt++)
#pragma unroll
        for (int ct = 0; ct < 8; ct++) acc[rt][ct] = (f32x4){0.f, 0.f, 0.f, 0.f};

#pragma unroll
    for (int ks = 0; ks < 4; ks++) {
#pragma unroll
        for (int ct = 0; ct < 8; ct++) {
            bf16x8 bf = *(bf16x8*)&Wl[(ct * 16 + mrow) * 136 + ks * 32 + quad * 8];
#pragma unroll
            for (int rt = 0; rt < 2; rt++)
                acc[rt][ct] = __builtin_amdgcn_mfma_f32_16x16x32_bf16(af[rt][ks], bf, acc[rt][ct], 0, 0, 0);
        }
    }

#pragma unroll
    for (int rt = 0; rt < 2; rt++) {
#pragma unroll
        for (int reg = 0; reg < 4; reg++) {
            int row = rbase + rt * 16 + quad * 4 + reg;
            if (row < n) {
                float dv = dinv[row];
#pragma unroll
                for (int ct = 0; ct < 8; ct++)
                    h[(long)row * D + ct * 16 + mrow] = f2bf(acc[rt][ct][reg] * dv);
            }
        }
    }
}

// ---------------- aggregation + epilogue (16-edge pipelined gather) ----------------
// 4 nodes per 256-thr block; one wave per node.
// lane = slot(0..3)*16 + chunk(0..15); each gather instr covers 4 edges (1 KB).
#define ACC4(v)                                          \
    {                                                    \
        acc0 += (f32x2){bflo2f((v).x), bfhi2f((v).x)};   \
        acc1 += (f32x2){bflo2f((v).y), bfhi2f((v).y)};   \
        acc2 += (f32x2){bflo2f((v).z), bfhi2f((v).z)};   \
        acc3 += (f32x2){bflo2f((v).w), bfhi2f((v).w)};   \
    }

__global__ __launch_bounds__(256) void k_aggregate(const uint4* __restrict__ h4, const float* __restrict__ x,
                                                   const float* __restrict__ dinv, const float* __restrict__ bias,
                                                   const int* __restrict__ offs,
                                                   const int* __restrict__ sorted_src,
                                                   float* __restrict__ out, int n) {
    int wave = threadIdx.x >> 6, lane = threadIdx.x & 63;
    int i = blockIdx.x * 4 + wave;
    if (i >= n) return;
    int slot = lane >> 4, chunk = lane & 15;
    int start = offs[i], m = offs[i + 1] - start;

    f32x2 acc0 = {0.f, 0.f}, acc1 = {0.f, 0.f}, acc2 = {0.f, 0.f}, acc3 = {0.f, 0.f};
    if (slot == 0) {  // self loop (scaled by dinv[i] at the end)
        uint4 v = h4[(long)i * 16 + chunk];
        ACC4(v);
    }

    int j0 = 0;
    if (m >= 16) {
        int ja = start + slot * 4;
        int e0 = sorted_src[ja], e1 = sorted_src[ja + 1], e2 = sorted_src[ja + 2], e3 = sorted_src[ja + 3];
        for (;;) {
            uint4 v0 = h4[(long)e0 * 16 + chunk];
            uint4 v1 = h4[(long)e1 * 16 + chunk];
            uint4 v2 = h4[(long)e2 * 16 + chunk];
            uint4 v3 = h4[(long)e3 * 16 + chunk];
            j0 += 16;
            bool more = (j0 + 16 <= m);
            if (more) {  // prefetch next iteration's indices while gathers are in flight
                int jb = start + j0 + slot * 4;
                e0 = sorted_src[jb]; e1 = sorted_src[jb + 1]; e2 = sorted_src[jb + 2]; e3 = sorted_src[jb + 3];
            }
            ACC4(v0); ACC4(v1); ACC4(v2); ACC4(v3);
            if (!more) break;
        }
    }
    if (j0 + 8 <= m) {
        int ja = start + j0 + slot * 2;
        int e0 = sorted_src[ja], e1 = sorted_src[ja + 1];
        uint4 v0 = h4[(long)e0 * 16 + chunk];
        uint4 v1 = h4[(long)e1 * 16 + chunk];
        ACC4(v0); ACC4(v1);
        j0 += 8;
    }
    for (int j = j0 + slot; j < m; j += 4) {
        int s = sorted_src[start + j];
        uint4 v = h4[(long)s * 16 + chunk];
        ACC4(v);
    }

    // sum the 4 slots (chunk preserved)
    f32x2 accA[4] = {acc0, acc1, acc2, acc3};
#pragma unroll
    for (int r = 0; r < 4; r++) {
        accA[r].x += __shfl_xor(accA[r].x, 16, 64);
        accA[r].x += __shfl_xor(accA[r].x, 32, 64);
        accA[r].y += __shfl_xor(accA[r].y, 16, 64);
        accA[r].y += __shfl_xor(accA[r].y, 32, 64);
    }

    // epilogue: slot writes dims chunk*8 + slot*2 + {0,1}  (uint index k == slot)
    float di = dinv[i];
    int dbase = chunk * 8 + slot * 2;
    float2 bb = *(const float2*)&bias[dbase];
    float2 xv = *(const float2*)&x[(long)i * D + dbase];
    float ax = accA[slot].x * di + bb.x;
    float ay = accA[slot].y * di + bb.y;
    ax = (ax >= 0.f) ? ax : NEG_SLOPE * ax;
    ay = (ay >= 0.f) ? ay : NEG_SLOPE * ay;
    float2 o;
    o.x = ax + xv.x;
    o.y = ay + xv.y;
    *(float2*)&out[(long)i * D + dbase] = o;
}

extern "C" void kernel_launch(void* const* d_in, const int* in_sizes, int n_in,
                              void* d_out, int out_size, void* d_ws, size_t ws_size,
                              hipStream_t stream) {
    const float* x = (const float*)d_in[0];
    const int* edge_index = (const int*)d_in[1];
    const float* W = (const float*)d_in[2];
    const float* bias = (const float*)d_in[3];
    float* out = (float*)d_out;

    int N = in_sizes[0] / D;
    int E = in_sizes[1] / 2;
    const int* src = edge_index;       // edge_index[0]
    const int* dst = edge_index + E;   // edge_index[1]
    int NB = (N + BSIZE - 1) >> BSHIFT;  // buckets (<=256 for N<=131072)

    char* ws = (char*)d_ws;
    size_t off = 0;
    auto alloc = [&](size_t bytes) {
        void* p = ws + off;
        off += (bytes + 15) & ~(size_t)15;
        return p;
    };
    int* offs = (int*)alloc((size_t)(N + 1) * 4);
    float* dinv = (float*)alloc((size_t)N * 4);
    int* bucketCnt = (int*)alloc((size_t)NB * 4);
    int* bucketBase = (int*)alloc((size_t)(NB + 1) * 4);
    int* bucketCursor = (int*)alloc((size_t)NB * 4);
    int* ebuf = (int*)alloc((size_t)E * 4);
    int* sorted_src = (int*)alloc((size_t)E * 4);
    unsigned short* Wt = (unsigned short*)alloc((size_t)D * D * 2);
    unsigned short* h = (unsigned short*)alloc((size_t)N * D * 2);

    int nbE = (E + 4095) / 4096;

    hipMemsetAsync(bucketCnt, 0, (size_t)NB * 4, stream);
    k_bucket_count<<<nbE + 64, 256, 0, stream>>>(dst, bucketCnt, E, NB, W, Wt);
    k_bucket_scan<<<1, 256, 0, stream>>>(bucketCnt, bucketBase, bucketCursor, offs, NB, N, E);
    k_bucket_scatter<<<nbE, 256, 0, stream>>>(src, dst, bucketCursor, ebuf, E, NB);
    k_bucket_csr<<<NB, 256, 0, stream>>>(ebuf, bucketBase, offs, dinv, sorted_src, N);
    k_gemm<<<(N + 127) / 128, 256, 0, stream>>>(x, Wt, dinv, h, N);
    k_aggregate<<<(N + 3) / 4, 256, 0, stream>>>((const uint4*)h, x, dinv, bias, offs, sorted_src, out, N);
}

// Round 6
// 231.008 us; speedup vs baseline: 1.1413x; 1.1413x over previous
//
#include <hip/hip_runtime.h>
#include <hip/hip_bf16.h>

#define D 128
#define NEG_SLOPE 0.1f
// bucket sort: 512 nodes per bucket; pack = (dstLocal<<17)|src  (valid: N < 2^17)
#define BSHIFT 9
#define BSIZE 512
#define SRCBITS 17
#define SRCMASK 0x1FFFF

typedef __attribute__((ext_vector_type(8))) short bf16x8;
typedef __attribute__((ext_vector_type(4))) float f32x4;
typedef __attribute__((ext_vector_type(2))) float f32x2;

__device__ inline unsigned short f2bf(float f) {
    unsigned u = __builtin_bit_cast(unsigned, f);
    u += 0x7fff + ((u >> 16) & 1);  // round-to-nearest-even
    return (unsigned short)(u >> 16);
}

// ---------------- bucket histogram (LDS-aggregated) + fused W transpose ----------------
__global__ __launch_bounds__(256) void k_bucket_count(const int* __restrict__ dst,
                                                      int* __restrict__ bucketCnt, int E, int NB,
                                                      const float* __restrict__ W,
                                                      unsigned short* __restrict__ Wt) {
    int b = blockIdx.x;
    int nbE = gridDim.x - 64;
    if (b >= nbE) {
        int t = (b - nbE) * 256 + threadIdx.x;  // 0..16383
        int k = t >> 7, nn = t & 127;
        Wt[nn * D + k] = f2bf(W[k * D + nn]);
        return;
    }
    __shared__ int hist[256];
    int t = threadIdx.x;
    hist[t] = 0;
    __syncthreads();
    const int4* dst4 = (const int4*)dst;
#pragma unroll
    for (int j = 0; j < 4; j++) {
        int i4 = b * 1024 + j * 256 + t;
        int e = i4 * 4;
        if (e + 4 <= E) {
            int4 d = dst4[i4];
            atomicAdd(&hist[d.x >> BSHIFT], 1);
            atomicAdd(&hist[d.y >> BSHIFT], 1);
            atomicAdd(&hist[d.z >> BSHIFT], 1);
            atomicAdd(&hist[d.w >> BSHIFT], 1);
        } else {
            for (int k = e; k < E; k++) atomicAdd(&hist[dst[k] >> BSHIFT], 1);
        }
    }
    __syncthreads();
    if (t < NB && hist[t]) atomicAdd(&bucketCnt[t], hist[t]);
}

// ---------------- scan bucket counts (1 block); init cursor; sentinels ----------------
__global__ __launch_bounds__(256) void k_bucket_scan(const int* __restrict__ bucketCnt,
                                                     int* __restrict__ bucketBase, int* __restrict__ bucketCursor,
                                                     int* __restrict__ offs, int NB, int N, int E) {
    __shared__ int sh[256];
    int t = threadIdx.x;
    int v = (t < NB) ? bucketCnt[t] : 0;
    sh[t] = v;
    __syncthreads();
    for (int d = 1; d < 256; d <<= 1) {
        int y = 0;
        if (t >= d) y = sh[t - d];
        __syncthreads();
        sh[t] += y;
        __syncthreads();
    }
    if (t < NB) {
        int excl = sh[t] - v;
        bucketBase[t] = excl;
        bucketCursor[t] = excl;
    }
    if (t == 0) {
        bucketBase[NB] = E;
        offs[N] = E;  // CSR sentinel
    }
}

// ---------------- bucket scatter: packed edges into bucket regions ----------------
__global__ __launch_bounds__(256) void k_bucket_scatter(const int* __restrict__ src, const int* __restrict__ dst,
                                                        int* __restrict__ bucketCursor,
                                                        int* __restrict__ ebuf, int E, int NB) {
    __shared__ int cntL[256], baseL[256], curL[256];
    int t = threadIdx.x;
    cntL[t] = 0;
    curL[t] = 0;
    __syncthreads();

    const int4* src4 = (const int4*)src;
    const int4* dst4 = (const int4*)dst;
    int sv[16], dv[16];
    int nval[4];
#pragma unroll
    for (int j = 0; j < 4; j++) {
        int i4 = blockIdx.x * 1024 + j * 256 + t;
        int e = i4 * 4;
        if (e + 4 <= E) {
            int4 s = src4[i4];
            int4 d = dst4[i4];
            sv[j * 4] = s.x; sv[j * 4 + 1] = s.y; sv[j * 4 + 2] = s.z; sv[j * 4 + 3] = s.w;
            dv[j * 4] = d.x; dv[j * 4 + 1] = d.y; dv[j * 4 + 2] = d.z; dv[j * 4 + 3] = d.w;
            nval[j] = 4;
        } else {
            int c = 0;
            for (int k = e; k < E; k++, c++) { sv[j * 4 + c] = src[k]; dv[j * 4 + c] = dst[k]; }
            nval[j] = c;
        }
    }
#pragma unroll
    for (int j = 0; j < 4; j++)
        for (int k = 0; k < nval[j]; k++) atomicAdd(&cntL[dv[j * 4 + k] >> BSHIFT], 1);
    __syncthreads();
    if (t < NB) {
        int c = cntL[t];
        if (c) baseL[t] = atomicAdd(&bucketCursor[t], c);
    }
    __syncthreads();
#pragma unroll
    for (int j = 0; j < 4; j++)
        for (int k = 0; k < nval[j]; k++) {
            int d = dv[j * 4 + k];
            int b = d >> BSHIFT;
            int slot = atomicAdd(&curL[b], 1);
            ebuf[baseL[b] + slot] = ((d & (BSIZE - 1)) << SRCBITS) | sv[j * 4 + k];
        }
}

// ---------------- per-bucket CSR build: offs, dinv, sorted_src ----------------
__global__ __launch_bounds__(256) void k_bucket_csr(const int* __restrict__ ebuf, const int* __restrict__ bucketBase,
                                                    int* __restrict__ offs, float* __restrict__ dinv,
                                                    int* __restrict__ sorted_src, int N) {
    __shared__ int deg[BSIZE];
    __shared__ int wsum[4];
    int b = blockIdx.x, t = threadIdx.x, lane = t & 63, wave = t >> 6;
    int estart = bucketBase[b], eend = bucketBase[b + 1];
    int nstart = b << BSHIFT;

    deg[t] = 0;
    deg[t + 256] = 0;
    __syncthreads();
    for (int e = estart + t; e < eend; e += 256) atomicAdd(&deg[ebuf[e] >> SRCBITS], 1);
    __syncthreads();

    int d0 = deg[2 * t], d1 = deg[2 * t + 1];
    int sum = d0 + d1;
    int inc = sum;
    for (int d = 1; d < 64; d <<= 1) {
        int y = __shfl_up(inc, d, 64);
        if (lane >= d) inc += y;
    }
    int texcl = inc - sum;
    if (lane == 63) wsum[wave] = inc;
    __syncthreads();
    int woff = 0;
    for (int w = 0; w < wave; w++) woff += wsum[w];
    int e0 = woff + texcl;

    int i = nstart + 2 * t;
    if (i < N) { offs[i] = estart + e0; dinv[i] = rsqrtf((float)(d0 + 1)); }
    if (i + 1 < N) { offs[i + 1] = estart + e0 + d0; dinv[i + 1] = rsqrtf((float)(d1 + 1)); }
    __syncthreads();
    deg[2 * t] = e0;
    deg[2 * t + 1] = e0 + d0;
    __syncthreads();
    for (int e = estart + t; e < eend; e += 256) {
        int v = ebuf[e];
        int pos = atomicAdd(&deg[v >> SRCBITS], 1);
        sorted_src[estart + pos] = v & SRCMASK;
    }
}

// ---------------- MFMA GEMM: h'(fp8 e4m3) = (x @ W) * dinv[row] ----------------
// h row layout (128 bytes): byte p = mrow*8 + ct holds col ct*16 + mrow
// (i.e. col(p) = (p&7)*16 + (p>>3)). Aggregate epilogue inverts this.
__global__ __launch_bounds__(256) void k_gemm(const float* __restrict__ x,
                                              const unsigned short* __restrict__ Wt,
                                              const float* __restrict__ dinv,
                                              unsigned char* __restrict__ h, int n) {
    __shared__ unsigned short Wl[D * 136];
    int t = threadIdx.x;
    const uint4* Wg4 = (const uint4*)Wt;
#pragma unroll
    for (int j = 0; j < 8; j++) {
        int c = t + 256 * j;
        int row = c >> 4, kg = c & 15;
        *(uint4*)&Wl[row * 136 + kg * 8] = Wg4[row * 16 + kg];
    }
    __syncthreads();

    int lane = t & 63, wave = t >> 6;
    int quad = lane >> 4, mrow = lane & 15;
    int rbase = blockIdx.x * 128 + wave * 32;

    const float4* x4 = (const float4*)x;
    float4 a0[2][4], a1[2][4];
#pragma unroll
    for (int rt = 0; rt < 2; rt++) {
        int row = rbase + rt * 16 + mrow;
        long rowl = (row < n) ? row : (n - 1);
#pragma unroll
        for (int ks = 0; ks < 4; ks++) {
            long base = rowl * 32 + ks * 8 + quad * 2;
            a0[rt][ks] = x4[base];
            a1[rt][ks] = x4[base + 1];
        }
    }
    bf16x8 af[2][4];
#pragma unroll
    for (int rt = 0; rt < 2; rt++)
#pragma unroll
        for (int ks = 0; ks < 4; ks++) {
            bf16x8 f;
            f[0] = (short)f2bf(a0[rt][ks].x); f[1] = (short)f2bf(a0[rt][ks].y);
            f[2] = (short)f2bf(a0[rt][ks].z); f[3] = (short)f2bf(a0[rt][ks].w);
            f[4] = (short)f2bf(a1[rt][ks].x); f[5] = (short)f2bf(a1[rt][ks].y);
            f[6] = (short)f2bf(a1[rt][ks].z); f[7] = (short)f2bf(a1[rt][ks].w);
            af[rt][ks] = f;
        }

    f32x4 acc[2][8];
#pragma unroll
    for (int rt = 0; rt < 2; rt++)
#pragma unroll
        for (int ct = 0; ct < 8; ct++) acc[rt][ct] = (f32x4){0.f, 0.f, 0.f, 0.f};

#pragma unroll
    for (int ks = 0; ks < 4; ks++) {
#pragma unroll
        for (int ct = 0; ct < 8; ct++) {
            bf16x8 bf = *(bf16x8*)&Wl[(ct * 16 + mrow) * 136 + ks * 32 + quad * 8];
#pragma unroll
            for (int rt = 0; rt < 2; rt++)
                acc[rt][ct] = __builtin_amdgcn_mfma_f32_16x16x32_bf16(af[rt][ks], bf, acc[rt][ct], 0, 0, 0);
        }
    }

    // epilogue: scale by dinv, pack 8 cols (ct=0..7) into 8 fp8 bytes at mrow*8
#pragma unroll
    for (int rt = 0; rt < 2; rt++) {
#pragma unroll
        for (int reg = 0; reg < 4; reg++) {
            int row = rbase + rt * 16 + quad * 4 + reg;
            if (row < n) {
                float dv = dinv[row];
                float a[8];
#pragma unroll
                for (int ct = 0; ct < 8; ct++) a[ct] = acc[rt][ct][reg] * dv;
                int w0 = __builtin_amdgcn_cvt_pk_fp8_f32(a[0], a[1], 0, false);
                w0 = __builtin_amdgcn_cvt_pk_fp8_f32(a[2], a[3], w0, true);
                int w1 = __builtin_amdgcn_cvt_pk_fp8_f32(a[4], a[5], 0, false);
                w1 = __builtin_amdgcn_cvt_pk_fp8_f32(a[6], a[7], w1, true);
                uint2 wv; wv.x = (unsigned)w0; wv.y = (unsigned)w1;
                *(uint2*)&h[(long)row * 128 + mrow * 8] = wv;
            }
        }
    }
}

// ---------------- aggregation + epilogue (fp8 gather, 8 slots x 8 chunks) ----------------
// 4 nodes per 256-thr block; one wave per node. lane = slot(0..7)*8 + chunk(0..7).
// Each gather instr: 8 rows x 128 B = 16 cache lines, 8 edges.
#define ACCV(v)                                                       \
    {                                                                 \
        acc2[0] += __builtin_amdgcn_cvt_pk_f32_fp8((int)(v).x, false);\
        acc2[1] += __builtin_amdgcn_cvt_pk_f32_fp8((int)(v).x, true); \
        acc2[2] += __builtin_amdgcn_cvt_pk_f32_fp8((int)(v).y, false);\
        acc2[3] += __builtin_amdgcn_cvt_pk_f32_fp8((int)(v).y, true); \
        acc2[4] += __builtin_amdgcn_cvt_pk_f32_fp8((int)(v).z, false);\
        acc2[5] += __builtin_amdgcn_cvt_pk_f32_fp8((int)(v).z, true); \
        acc2[6] += __builtin_amdgcn_cvt_pk_f32_fp8((int)(v).w, false);\
        acc2[7] += __builtin_amdgcn_cvt_pk_f32_fp8((int)(v).w, true); \
    }

__global__ __launch_bounds__(256) void k_aggregate(const uint4* __restrict__ h4, const float* __restrict__ x,
                                                   const float* __restrict__ dinv, const float* __restrict__ bias,
                                                   const int* __restrict__ offs,
                                                   const int* __restrict__ sorted_src,
                                                   float* __restrict__ out, int n) {
    int wave = threadIdx.x >> 6, lane = threadIdx.x & 63;
    int i = blockIdx.x * 4 + wave;
    if (i >= n) return;
    int slot = lane >> 3, chunk = lane & 7;
    int start = offs[i], m = offs[i + 1] - start;

    f32x2 acc2[8];
#pragma unroll
    for (int r = 0; r < 8; r++) acc2[r] = (f32x2){0.f, 0.f};
    if (slot == 0) {  // self loop (scaled by dinv[i] at the end)
        uint4 v = h4[(long)i * 8 + chunk];
        ACCV(v);
    }

    int j0 = 0;
    if (m >= 16) {
        int ja = start + slot;
        int e0 = sorted_src[ja], e1 = sorted_src[ja + 8];
        for (;;) {
            uint4 v0 = h4[(long)e0 * 8 + chunk];
            uint4 v1 = h4[(long)e1 * 8 + chunk];
            j0 += 16;
            bool more = (j0 + 16 <= m);
            if (more) {  // prefetch next indices while gathers are in flight
                int jb = start + j0 + slot;
                e0 = sorted_src[jb];
                e1 = sorted_src[jb + 8];
            }
            ACCV(v0);
            ACCV(v1);
            if (!more) break;
        }
    }
    if (j0 + 8 <= m) {
        int e = sorted_src[start + j0 + slot];
        uint4 v = h4[(long)e * 8 + chunk];
        ACCV(v);
        j0 += 8;
    }
    for (int j = j0 + slot; j < m; j += 8) {
        int e = sorted_src[start + j];
        uint4 v = h4[(long)e * 8 + chunk];
        ACCV(v);
    }

    // reduce over slots (lane bits 3..5), chunk preserved
#pragma unroll
    for (int r = 0; r < 8; r++) {
        acc2[r].x += __shfl_xor(acc2[r].x, 8, 64);
        acc2[r].x += __shfl_xor(acc2[r].x, 16, 64);
        acc2[r].x += __shfl_xor(acc2[r].x, 32, 64);
        acc2[r].y += __shfl_xor(acc2[r].y, 8, 64);
        acc2[r].y += __shfl_xor(acc2[r].y, 16, 64);
        acc2[r].y += __shfl_xor(acc2[r].y, 32, 64);
    }

    // lane keeps q=slot (col slot*16+chunk*2) and q=slot+8 (col +1)
    int s1 = slot >> 1;
    f32x2 eL = (s1 == 0) ? acc2[0] : (s1 == 1) ? acc2[1] : (s1 == 2) ? acc2[2] : acc2[3];
    f32x2 eH = (s1 == 0) ? acc2[4] : (s1 == 1) ? acc2[5] : (s1 == 2) ? acc2[6] : acc2[7];
    float ax = (slot & 1) ? eL.y : eL.x;
    float ay = (slot & 1) ? eH.y : eH.x;

    float di = dinv[i];
    int dbase = slot * 16 + chunk * 2;
    float2 bb = *(const float2*)&bias[dbase];
    float2 xv = *(const float2*)&x[(long)i * D + dbase];
    ax = ax * di + bb.x;
    ay = ay * di + bb.y;
    ax = (ax >= 0.f) ? ax : NEG_SLOPE * ax;
    ay = (ay >= 0.f) ? ay : NEG_SLOPE * ay;
    float2 o;
    o.x = ax + xv.x;
    o.y = ay + xv.y;
    *(float2*)&out[(long)i * D + dbase] = o;
}

extern "C" void kernel_launch(void* const* d_in, const int* in_sizes, int n_in,
                              void* d_out, int out_size, void* d_ws, size_t ws_size,
                              hipStream_t stream) {
    const float* x = (const float*)d_in[0];
    const int* edge_index = (const int*)d_in[1];
    const float* W = (const float*)d_in[2];
    const float* bias = (const float*)d_in[3];
    float* out = (float*)d_out;

    int N = in_sizes[0] / D;
    int E = in_sizes[1] / 2;
    const int* src = edge_index;       // edge_index[0]
    const int* dst = edge_index + E;   // edge_index[1]
    int NB = (N + BSIZE - 1) >> BSHIFT;

    char* ws = (char*)d_ws;
    size_t off = 0;
    auto alloc = [&](size_t bytes) {
        void* p = ws + off;
        off += (bytes + 15) & ~(size_t)15;
        return p;
    };
    int* offs = (int*)alloc((size_t)(N + 1) * 4);
    float* dinv = (float*)alloc((size_t)N * 4);
    int* bucketCnt = (int*)alloc((size_t)NB * 4);
    int* bucketBase = (int*)alloc((size_t)(NB + 1) * 4);
    int* bucketCursor = (int*)alloc((size_t)NB * 4);
    int* ebuf = (int*)alloc((size_t)E * 4);
    int* sorted_src = (int*)alloc((size_t)E * 4);
    unsigned short* Wt = (unsigned short*)alloc((size_t)D * D * 2);
    unsigned char* h = (unsigned char*)alloc((size_t)N * D);

    int nbE = (E + 4095) / 4096;

    hipMemsetAsync(bucketCnt, 0, (size_t)NB * 4, stream);
    k_bucket_count<<<nbE + 64, 256, 0, stream>>>(dst, bucketCnt, E, NB, W, Wt);
    k_bucket_scan<<<1, 256, 0, stream>>>(bucketCnt, bucketBase, bucketCursor, offs, NB, N, E);
    k_bucket_scatter<<<nbE, 256, 0, stream>>>(src, dst, bucketCursor, ebuf, E, NB);
    k_bucket_csr<<<NB, 256, 0, stream>>>(ebuf, bucketBase, offs, dinv, sorted_src, N);
    k_gemm<<<(N + 127) / 128, 256, 0, stream>>>(x, Wt, dinv, h, N);
    k_aggregate<<<(N + 3) / 4, 256, 0, stream>>>((const uint4*)h, x, dinv, bias, offs, sorted_src, out, N);
}